// Round 1
// baseline (125.819 us; speedup 1.0000x reference)
//
#include <hip/hip_runtime.h>
#include <stdint.h>

#define NN 4096
#define NB 32          // NN / 128
#define BK 32          // K-step (one 16x16x32 MFMA per step)
#define NTILT 528      // NB*(NB+1)/2 lower tiles
#define NTOT 1024      // NB*NB

typedef __bf16 bf16x8 __attribute__((ext_vector_type(8)));
typedef float f32x4 __attribute__((ext_vector_type(4)));
typedef unsigned short ushort8 __attribute__((ext_vector_type(8)));

// RTNE fp32 -> bf16
__device__ __forceinline__ unsigned short f2bf(float x) {
    union { float f; unsigned int u; } v; v.f = x;
    unsigned int u = v.u;
    u += 0x7fffu + ((u >> 16) & 1u);
    return (unsigned short)(u >> 16);
}

// async global->LDS, 16B per lane; LDS dest is wave-uniform base + lane*16
#define GLOAD16(g, l) __builtin_amdgcn_global_load_lds( \
    (const __attribute__((address_space(1))) unsigned int*)(g), \
    (__attribute__((address_space(3))) unsigned int*)(l), 16, 0, 0)

// ---- prep: A fp32 row-major -> bf16 row-major ----
__global__ void convert_a(const float* __restrict__ A, unsigned short* __restrict__ Ab) {
    size_t i = (size_t)blockIdx.x * blockDim.x + threadIdx.x; // 8 elems per thread
    const float4* pa = reinterpret_cast<const float4*>(A) + i * 2;
    float4 x0 = pa[0], x1 = pa[1];
    ushort8 o;
    o[0] = f2bf(x0.x); o[1] = f2bf(x0.y); o[2] = f2bf(x0.z); o[3] = f2bf(x0.w);
    o[4] = f2bf(x1.x); o[5] = f2bf(x1.y); o[6] = f2bf(x1.z); o[7] = f2bf(x1.w);
    *reinterpret_cast<ushort8*>(Ab + i * 8) = o;
}

// ---- prep: B fp32 [K][N] -> Bt bf16 [N][K] ----
__global__ void transpose_b(const float* __restrict__ B, unsigned short* __restrict__ Bt) {
    __shared__ float tile[64][65];
    int n0 = blockIdx.x * 64;
    int k0 = blockIdx.y * 64;
    int tx = threadIdx.x;  // 0..63 (one wave per ty)
    int ty = threadIdx.y;  // 0..3
#pragma unroll
    for (int r = 0; r < 16; ++r) {
        int k = ty + r * 4;
        tile[k][tx] = B[(size_t)(k0 + k) * NN + n0 + tx];
    }
    __syncthreads();
#pragma unroll
    for (int r = 0; r < 16; ++r) {
        int n = ty + r * 4;
        Bt[(size_t)(n0 + n) * NN + k0 + tx] = f2bf(tile[tx][n]);
    }
}

// ---- triangular GEMM: C = A*B, lower tiles only; upper tiles zero-filled ----
__global__ __launch_bounds__(256) void trimm(const unsigned short* __restrict__ Ab,
                                             const unsigned short* __restrict__ Bt,
                                             float* __restrict__ C) {
    int bid = blockIdx.x;
    int tid = threadIdx.x;
    int lane = tid & 63;
    int w = tid >> 6;

    int bi, bj;
    if (bid >= NTILT) {
        // strict upper tile: zero-fill 128x128
        int t = bid - NTILT;
        int r = 0, cnt = NB - 1;
        while (t >= cnt) { t -= cnt; ++r; --cnt; }
        bi = r; bj = r + 1 + t;
        float4 z = make_float4(0.f, 0.f, 0.f, 0.f);
        float4* cp = reinterpret_cast<float4*>(C + (size_t)bi * 128 * NN + (size_t)bj * 128);
#pragma unroll
        for (int i2 = 0; i2 < 16; ++i2) {
            int slot = tid + i2 * 256;
            int row = slot >> 5, c4 = slot & 31;
            cp[(size_t)row * (NN / 4) + c4] = z;
        }
        return;
    }
    {
        // lower tiles ordered by descending work d = bi-bj (heaviest first)
        int t = bid, d = NB - 1, cnt = 1;
        while (t >= cnt) { t -= cnt; --d; cnt = NB - d; }
        bj = t; bi = t + d;
    }

    __shared__ unsigned short As[128 * BK];
    __shared__ unsigned short Bs[128 * BK];

    int wr = w >> 1, wc = w & 1;

    // staging: As/Bs linear [row][k], 64B rows; wave w covers LDS bytes [w*2048, w*2048+2048)
    int srow = w * 32 + (lane >> 2);
    int skoff = (lane & 3) * 8;
    const unsigned short* gA0 = Ab + (size_t)(bi * 128 + srow) * NN + skoff;
    const unsigned short* gA1 = gA0 + (size_t)16 * NN;
    const unsigned short* gB0 = Bt + (size_t)(bj * 128 + srow) * NN + skoff;
    const unsigned short* gB1 = gB0 + (size_t)16 * NN;
    unsigned short* lA0 = As + w * 1024;
    unsigned short* lA1 = lA0 + 512;
    unsigned short* lB0 = Bs + w * 1024;
    unsigned short* lB1 = lB0 + 512;

    f32x4 acc[4][4];
#pragma unroll
    for (int mi = 0; mi < 4; ++mi)
#pragma unroll
        for (int ni = 0; ni < 4; ++ni)
            acc[mi][ni] = (f32x4){0.f, 0.f, 0.f, 0.f};

    const int k_lo = bj * 128;          // B rows < bj*128 are structurally zero
    const int k_hi = (bi + 1) * 128;    // A cols > bi*128+127 are structurally zero

    int arow = wr * 64 + (lane & 15);
    int brow = wc * 64 + (lane & 15);
    int kq = (lane >> 4) * 8;

    for (int kt = k_lo; kt < k_hi; kt += BK) {
        GLOAD16(gA0 + kt, lA0);
        GLOAD16(gA1 + kt, lA1);
        GLOAD16(gB0 + kt, lB0);
        GLOAD16(gB1 + kt, lB1);
        __syncthreads();

        bf16x8 af[4], bfr[4];
#pragma unroll
        for (int mi = 0; mi < 4; ++mi)
            af[mi] = *reinterpret_cast<const bf16x8*>(&As[(arow + mi * 16) * BK + kq]);
#pragma unroll
        for (int ni = 0; ni < 4; ++ni)
            bfr[ni] = *reinterpret_cast<const bf16x8*>(&Bs[(brow + ni * 16) * BK + kq]);
#pragma unroll
        for (int mi = 0; mi < 4; ++mi)
#pragma unroll
            for (int ni = 0; ni < 4; ++ni)
                acc[mi][ni] = __builtin_amdgcn_mfma_f32_16x16x32_bf16(af[mi], bfr[ni], acc[mi][ni], 0, 0, 0);
        __syncthreads();
    }

    // epilogue: C/D layout col = lane&15, row = (lane>>4)*4 + reg
    int crow0 = bi * 128 + wr * 64 + (lane >> 4) * 4;
    int ccol0 = bj * 128 + wc * 64 + (lane & 15);
#pragma unroll
    for (int mi = 0; mi < 4; ++mi)
#pragma unroll
        for (int ni = 0; ni < 4; ++ni) {
            float* cp = C + (size_t)(crow0 + mi * 16) * NN + ccol0 + ni * 16;
#pragma unroll
            for (int r2 = 0; r2 < 4; ++r2)
                cp[(size_t)r2 * NN] = acc[mi][ni][r2];
        }
}

extern "C" void kernel_launch(void* const* d_in, const int* in_sizes, int n_in,
                              void* d_out, int out_size, void* d_ws, size_t ws_size,
                              hipStream_t stream) {
    const float* A = (const float*)d_in[0];
    const float* B = (const float*)d_in[1];
    float* C = (float*)d_out;
    unsigned short* Ab = (unsigned short*)d_ws;            // 32 MB bf16 A
    unsigned short* Bt = Ab + (size_t)NN * NN;             // 32 MB bf16 B^T
    convert_a<<<8192, 256, 0, stream>>>(A, Ab);
    transpose_b<<<dim3(64, 64), dim3(64, 4), 0, stream>>>(B, Bt);
    trimm<<<NTOT, 256, 0, stream>>>(Ab, Bt, C);
}

// Round 2
// 90.192 us; speedup vs baseline: 1.3950x; 1.3950x over previous
//
#include <hip/hip_runtime.h>
#include <stdint.h>

#define NN 4096
#define NB 32          // NN / 128
#define BK 32          // K-step (one 16x16x32 MFMA per step)

// trimm grid layout: [0,272) heavy half-units (d>=16), [272,664) light tiles
// (d<=15), [664,1160) strict-upper zero tiles.
#define NHEAVY 136
#define NHUNITS 272
#define NLIGHT 392
#define ZBASE 664
#define TGRID 1160

// prep grid: [0,4096) A rows, [4096,8192) B 64x64 subtiles, [8192,8328) heavy-C zero
#define PGRID 8328

typedef __bf16 bf16x8 __attribute__((ext_vector_type(8)));
typedef float f32x4 __attribute__((ext_vector_type(4)));
typedef unsigned short ushort8 __attribute__((ext_vector_type(8)));

// RTNE fp32 -> bf16
__device__ __forceinline__ unsigned short f2bf(float x) {
    union { float f; unsigned int u; } v; v.f = x;
    unsigned int u = v.u;
    u += 0x7fffu + ((u >> 16) & 1u);
    return (unsigned short)(u >> 16);
}

// async global->LDS, 16B per lane; LDS dest is wave-uniform base + lane*16
#define GLOAD16(g, l) __builtin_amdgcn_global_load_lds( \
    (const __attribute__((address_space(1))) unsigned int*)(g), \
    (__attribute__((address_space(3))) unsigned int*)(l), 16, 0, 0)

// heavy tile index h (0..135) -> (bi,bj), d descending from 31 to 16
__device__ __forceinline__ void heavy_map(int h, int& bi, int& bj) {
    int t = h, d = NB - 1;
    while (t >= NB - d) { t -= NB - d; --d; }
    bj = t; bi = t + d;
}

// ---- fused prep: A lower-prefix convert, B lower transpose-convert, heavy-C zero ----
__global__ __launch_bounds__(256) void prep(const float* __restrict__ A,
                                            const float* __restrict__ B,
                                            unsigned short* __restrict__ Ab,
                                            unsigned short* __restrict__ Bt,
                                            float* __restrict__ C) {
    __shared__ float tile[64][65];
    int bid = blockIdx.x;
    int tid = threadIdx.x;

    if (bid < 4096) {
        // A row i: convert fp32 prefix [0, ((i>>7)+1)*128) to bf16
        int i = bid;
        int nslots = (((i >> 7) + 1) * 128) >> 3;   // 8 floats per slot
        const float4* src = reinterpret_cast<const float4*>(A + (size_t)i * NN);
        unsigned short* dst = Ab + (size_t)i * NN;
        for (int p = tid; p < nslots; p += 256) {
            float4 x0 = src[p * 2], x1 = src[p * 2 + 1];
            ushort8 o;
            o[0] = f2bf(x0.x); o[1] = f2bf(x0.y); o[2] = f2bf(x0.z); o[3] = f2bf(x0.w);
            o[4] = f2bf(x1.x); o[5] = f2bf(x1.y); o[6] = f2bf(x1.z); o[7] = f2bf(x1.w);
            *reinterpret_cast<ushort8*>(dst + p * 8) = o;
        }
        return;
    }
    if (bid < 8192) {
        // B 64x64 subtile transpose: needed iff k64 >= (n64 & ~1)  (128-tile lower superset)
        int s = bid - 4096;
        int n64 = s >> 6, k64 = s & 63;
        if (k64 < (n64 & ~1)) return;
        int n0 = n64 * 64, k0 = k64 * 64;
        int tx = tid & 63, ty = tid >> 6;
#pragma unroll
        for (int r = 0; r < 16; ++r) {
            int k = ty + r * 4;
            tile[k][tx] = B[(size_t)(k0 + k) * NN + n0 + tx];
        }
        __syncthreads();
#pragma unroll
        for (int r = 0; r < 16; ++r) {
            int n = ty + r * 4;
            Bt[(size_t)(n0 + n) * NN + k0 + tx] = f2bf(tile[tx][n]);
        }
        return;
    }
    // zero-init heavy C tile (atomicAdd targets; re-zeroed every call)
    int h = bid - 8192;
    int bi, bj; heavy_map(h, bi, bj);
    float4 z = make_float4(0.f, 0.f, 0.f, 0.f);
    float4* cp = reinterpret_cast<float4*>(C + (size_t)bi * 128 * NN + (size_t)bj * 128);
#pragma unroll
    for (int i2 = 0; i2 < 16; ++i2) {
        int slot = tid + i2 * 256;
        int row = slot >> 5, c4 = slot & 31;
        cp[(size_t)row * (NN / 4) + c4] = z;
    }
}

// ---- triangular GEMM with 2-way split-K on heavy tiles ----
__global__ __launch_bounds__(256) void trimm(const unsigned short* __restrict__ Ab,
                                             const unsigned short* __restrict__ Bt,
                                             float* __restrict__ C) {
    int bid = blockIdx.x;
    int tid = threadIdx.x;
    int lane = tid & 63;
    int w = tid >> 6;

    int bi, bj;
    bool heavy = false;
    int k_lo, k_hi;

    if (bid >= ZBASE) {
        // strict upper tile: zero-fill 128x128
        int t = bid - ZBASE;
        int r = 0, cnt = NB - 1;
        while (t >= cnt) { t -= cnt; ++r; --cnt; }
        bi = r; bj = r + 1 + t;
        float4 z = make_float4(0.f, 0.f, 0.f, 0.f);
        float4* cp = reinterpret_cast<float4*>(C + (size_t)bi * 128 * NN + (size_t)bj * 128);
#pragma unroll
        for (int i2 = 0; i2 < 16; ++i2) {
            int slot = tid + i2 * 256;
            int row = slot >> 5, c4 = slot & 31;
            cp[(size_t)row * (NN / 4) + c4] = z;
        }
        return;
    }
    if (bid < NHUNITS) {
        // heavy half-unit: tile h = bid>>1, K-half = bid&1
        heavy = true;
        int h = bid >> 1, half = bid & 1;
        heavy_map(h, bi, bj);
        k_lo = bj * 128;
        k_hi = (bi + 1) * 128;
        int len = (k_hi - k_lo) >> 1;      // multiple of 64 -> multiple of BK
        if (half == 0) k_hi = k_lo + len;
        else           k_lo = k_lo + len;
    } else {
        // light tile, d = 15..0 descending
        int t = bid - NHUNITS, d = 15;
        while (t >= NB - d) { t -= NB - d; --d; }
        bj = t; bi = t + d;
        k_lo = bj * 128;
        k_hi = (bi + 1) * 128;
    }

    __shared__ unsigned short As[128 * BK];
    __shared__ unsigned short Bs[128 * BK];

    int wr = w >> 1, wc = w & 1;

    int srow = w * 32 + (lane >> 2);
    int skoff = (lane & 3) * 8;
    const unsigned short* gA0 = Ab + (size_t)(bi * 128 + srow) * NN + skoff;
    const unsigned short* gA1 = gA0 + (size_t)16 * NN;
    const unsigned short* gB0 = Bt + (size_t)(bj * 128 + srow) * NN + skoff;
    const unsigned short* gB1 = gB0 + (size_t)16 * NN;
    unsigned short* lA0 = As + w * 1024;
    unsigned short* lA1 = lA0 + 512;
    unsigned short* lB0 = Bs + w * 1024;
    unsigned short* lB1 = lB0 + 512;

    f32x4 acc[4][4];
#pragma unroll
    for (int mi = 0; mi < 4; ++mi)
#pragma unroll
        for (int ni = 0; ni < 4; ++ni)
            acc[mi][ni] = (f32x4){0.f, 0.f, 0.f, 0.f};

    int arow = wr * 64 + (lane & 15);
    int brow = wc * 64 + (lane & 15);
    int kq = (lane >> 4) * 8;

    for (int kt = k_lo; kt < k_hi; kt += BK) {
        GLOAD16(gA0 + kt, lA0);
        GLOAD16(gA1 + kt, lA1);
        GLOAD16(gB0 + kt, lB0);
        GLOAD16(gB1 + kt, lB1);
        __syncthreads();

        bf16x8 af[4], bfr[4];
#pragma unroll
        for (int mi = 0; mi < 4; ++mi)
            af[mi] = *reinterpret_cast<const bf16x8*>(&As[(arow + mi * 16) * BK + kq]);
#pragma unroll
        for (int ni = 0; ni < 4; ++ni)
            bfr[ni] = *reinterpret_cast<const bf16x8*>(&Bs[(brow + ni * 16) * BK + kq]);
#pragma unroll
        for (int mi = 0; mi < 4; ++mi)
#pragma unroll
            for (int ni = 0; ni < 4; ++ni)
                acc[mi][ni] = __builtin_amdgcn_mfma_f32_16x16x32_bf16(af[mi], bfr[ni], acc[mi][ni], 0, 0, 0);
        __syncthreads();
    }

    // epilogue: C/D layout col = lane&15, row = (lane>>4)*4 + reg
    int crow0 = bi * 128 + wr * 64 + (lane >> 4) * 4;
    int ccol0 = bj * 128 + wc * 64 + (lane & 15);
    if (heavy) {
#pragma unroll
        for (int mi = 0; mi < 4; ++mi)
#pragma unroll
            for (int ni = 0; ni < 4; ++ni) {
                float* cp = C + (size_t)(crow0 + mi * 16) * NN + ccol0 + ni * 16;
#pragma unroll
                for (int r2 = 0; r2 < 4; ++r2)
                    atomicAdd(&cp[(size_t)r2 * NN], acc[mi][ni][r2]);
            }
    } else {
#pragma unroll
        for (int mi = 0; mi < 4; ++mi)
#pragma unroll
            for (int ni = 0; ni < 4; ++ni) {
                float* cp = C + (size_t)(crow0 + mi * 16) * NN + ccol0 + ni * 16;
#pragma unroll
                for (int r2 = 0; r2 < 4; ++r2)
                    cp[(size_t)r2 * NN] = acc[mi][ni][r2];
            }
    }
}

extern "C" void kernel_launch(void* const* d_in, const int* in_sizes, int n_in,
                              void* d_out, int out_size, void* d_ws, size_t ws_size,
                              hipStream_t stream) {
    const float* A = (const float*)d_in[0];
    const float* B = (const float*)d_in[1];
    float* C = (float*)d_out;
    unsigned short* Ab = (unsigned short*)d_ws;            // 32 MB bf16 A (lower tiles valid)
    unsigned short* Bt = Ab + (size_t)NN * NN;             // 32 MB bf16 B^T (needed tiles valid)
    prep<<<PGRID, 256, 0, stream>>>(A, B, Ab, Bt, C);
    trimm<<<TGRID, 256, 0, stream>>>(Ab, Bt, C);
}

// Round 3
// 85.859 us; speedup vs baseline: 1.4654x; 1.0505x over previous
//
#include <hip/hip_runtime.h>
#include <stdint.h>

#define NN 4096
#define NB 32          // NN / 128
#define BK 32          // K-step (one 16x16x32 MFMA per step)

// trimm grid layout: [0,272) heavy half-units (d>=16), [272,664) light tiles
// (d<=15), [664,1160) strict-upper zero tiles.
#define NHEAVY 136
#define NHUNITS 272
#define ZBASE 664
#define TGRID 1160

// prep grid: [0,4096) A rows, [4096,8192) B 64x64 subtiles, [8192,8328) heavy-C zero
#define PGRID 8328

typedef __bf16 bf16x8 __attribute__((ext_vector_type(8)));
typedef float f32x4 __attribute__((ext_vector_type(4)));
typedef unsigned short ushort8 __attribute__((ext_vector_type(8)));

// RTNE fp32 -> bf16
__device__ __forceinline__ unsigned short f2bf(float x) {
    union { float f; unsigned int u; } v; v.f = x;
    unsigned int u = v.u;
    u += 0x7fffu + ((u >> 16) & 1u);
    return (unsigned short)(u >> 16);
}

// async global->LDS, 16B per lane; LDS dest is wave-uniform base + lane*16
#define GLOAD16(g, l) __builtin_amdgcn_global_load_lds( \
    (const __attribute__((address_space(1))) unsigned int*)(g), \
    (__attribute__((address_space(3))) unsigned int*)(l), 16, 0, 0)

// heavy tile index h (0..135) -> (bi,bj), d descending from 31 to 16
__device__ __forceinline__ void heavy_map(int h, int& bi, int& bj) {
    int t = h, d = NB - 1;
    while (t >= NB - d) { t -= NB - d; --d; }
    bj = t; bi = t + d;
}

// ---- fused prep: A lower-prefix convert, B lower transpose-convert, heavy-C zero ----
__global__ __launch_bounds__(256) void prep(const float* __restrict__ A,
                                            const float* __restrict__ B,
                                            unsigned short* __restrict__ Ab,
                                            unsigned short* __restrict__ Bt,
                                            float* __restrict__ C) {
    __shared__ float tile[64][65];
    int bid = blockIdx.x;
    int tid = threadIdx.x;

    if (bid < 4096) {
        // A row i: convert fp32 prefix [0, ((i>>7)+1)*128) to bf16
        int i = bid;
        int nslots = (((i >> 7) + 1) * 128) >> 3;   // 8 floats per slot
        const float4* src = reinterpret_cast<const float4*>(A + (size_t)i * NN);
        unsigned short* dst = Ab + (size_t)i * NN;
        for (int p = tid; p < nslots; p += 256) {
            float4 x0 = src[p * 2], x1 = src[p * 2 + 1];
            ushort8 o;
            o[0] = f2bf(x0.x); o[1] = f2bf(x0.y); o[2] = f2bf(x0.z); o[3] = f2bf(x0.w);
            o[4] = f2bf(x1.x); o[5] = f2bf(x1.y); o[6] = f2bf(x1.z); o[7] = f2bf(x1.w);
            *reinterpret_cast<ushort8*>(dst + p * 8) = o;
        }
        return;
    }
    if (bid < 8192) {
        // B 64x64 subtile transpose: needed iff k64 >= (n64 & ~1)  (128-tile lower superset)
        int s = bid - 4096;
        int n64 = s >> 6, k64 = s & 63;
        if (k64 < (n64 & ~1)) return;
        int n0 = n64 * 64, k0 = k64 * 64;
        int tx = tid & 63, ty = tid >> 6;
#pragma unroll
        for (int r = 0; r < 16; ++r) {
            int k = ty + r * 4;
            tile[k][tx] = B[(size_t)(k0 + k) * NN + n0 + tx];
        }
        __syncthreads();
#pragma unroll
        for (int r = 0; r < 16; ++r) {
            int n = ty + r * 4;
            Bt[(size_t)(n0 + n) * NN + k0 + tx] = f2bf(tile[tx][n]);
        }
        return;
    }
    // zero-init heavy C tile (atomicAdd targets; re-zeroed every call)
    int h = bid - 8192;
    int bi, bj; heavy_map(h, bi, bj);
    float4 z = make_float4(0.f, 0.f, 0.f, 0.f);
    float4* cp = reinterpret_cast<float4*>(C + (size_t)bi * 128 * NN + (size_t)bj * 128);
#pragma unroll
    for (int i2 = 0; i2 < 16; ++i2) {
        int slot = tid + i2 * 256;
        int row = slot >> 5, c4 = slot & 31;
        cp[(size_t)row * (NN / 4) + c4] = z;
    }
}

// ---- triangular GEMM, 2-way split-K on heavy tiles, double-buffered pipeline ----
__global__ __launch_bounds__(256) void trimm(const unsigned short* __restrict__ Ab,
                                             const unsigned short* __restrict__ Bt,
                                             float* __restrict__ C) {
    int bid = blockIdx.x;
    int tid = threadIdx.x;
    int lane = tid & 63;
    int w = tid >> 6;

    int bi, bj;
    bool heavy = false;
    int k_lo, k_hi;

    if (bid >= ZBASE) {
        // strict upper tile: zero-fill 128x128
        int t = bid - ZBASE;
        int r = 0, cnt = NB - 1;
        while (t >= cnt) { t -= cnt; ++r; --cnt; }
        bi = r; bj = r + 1 + t;
        float4 z = make_float4(0.f, 0.f, 0.f, 0.f);
        float4* cp = reinterpret_cast<float4*>(C + (size_t)bi * 128 * NN + (size_t)bj * 128);
#pragma unroll
        for (int i2 = 0; i2 < 16; ++i2) {
            int slot = tid + i2 * 256;
            int row = slot >> 5, c4 = slot & 31;
            cp[(size_t)row * (NN / 4) + c4] = z;
        }
        return;
    }
    if (bid < NHUNITS) {
        // heavy half-unit: tile h = bid>>1, K-half = bid&1
        heavy = true;
        int h = bid >> 1, half = bid & 1;
        heavy_map(h, bi, bj);
        k_lo = bj * 128;
        k_hi = (bi + 1) * 128;
        int len = (k_hi - k_lo) >> 1;      // multiple of 64 -> multiple of BK
        if (half == 0) k_hi = k_lo + len;
        else           k_lo = k_lo + len;
    } else {
        // light tile, d = 15..0 descending
        int t = bid - NHUNITS, d = 15;
        while (t >= NB - d) { t -= NB - d; --d; }
        bj = t; bi = t + d;
        k_lo = bj * 128;
        k_hi = (bi + 1) * 128;
    }

    __shared__ unsigned short As[2][128 * BK];
    __shared__ unsigned short Bs[2][128 * BK];

    int wr = w >> 1, wc = w & 1;

    int srow = w * 32 + (lane >> 2);
    int skoff = (lane & 3) * 8;
    const unsigned short* gA0 = Ab + (size_t)(bi * 128 + srow) * NN + skoff;
    const unsigned short* gA1 = gA0 + (size_t)16 * NN;
    const unsigned short* gB0 = Bt + (size_t)(bj * 128 + srow) * NN + skoff;
    const unsigned short* gB1 = gB0 + (size_t)16 * NN;

    f32x4 acc[4][4];
#pragma unroll
    for (int mi = 0; mi < 4; ++mi)
#pragma unroll
        for (int ni = 0; ni < 4; ++ni)
            acc[mi][ni] = (f32x4){0.f, 0.f, 0.f, 0.f};

    int arow = wr * 64 + (lane & 15);
    int brow = wc * 64 + (lane & 15);
    int kq = (lane >> 4) * 8;

    // prologue: stage first K-step into buf 0
    {
        unsigned short* a = &As[0][w * 1024];
        unsigned short* b = &Bs[0][w * 1024];
        GLOAD16(gA0 + k_lo, a);
        GLOAD16(gA1 + k_lo, a + 512);
        GLOAD16(gB0 + k_lo, b);
        GLOAD16(gB1 + k_lo, b + 512);
    }
    int cur = 0;

    for (int kt = k_lo; kt < k_hi; kt += BK) {
        // drains vmcnt(0): buf[cur] staged; also: all waves done reading buf[cur^1]
        __syncthreads();

        if (kt + BK < k_hi) {
            unsigned short* a = &As[cur ^ 1][w * 1024];
            unsigned short* b = &Bs[cur ^ 1][w * 1024];
            GLOAD16(gA0 + kt + BK, a);
            GLOAD16(gA1 + kt + BK, a + 512);
            GLOAD16(gB0 + kt + BK, b);
            GLOAD16(gB1 + kt + BK, b + 512);
        }

        bf16x8 af[4], bfr[4];
#pragma unroll
        for (int mi = 0; mi < 4; ++mi)
            af[mi] = *reinterpret_cast<const bf16x8*>(&As[cur][(arow + mi * 16) * BK + kq]);
#pragma unroll
        for (int ni = 0; ni < 4; ++ni)
            bfr[ni] = *reinterpret_cast<const bf16x8*>(&Bs[cur][(brow + ni * 16) * BK + kq]);
#pragma unroll
        for (int mi = 0; mi < 4; ++mi)
#pragma unroll
            for (int ni = 0; ni < 4; ++ni)
                acc[mi][ni] = __builtin_amdgcn_mfma_f32_16x16x32_bf16(af[mi], bfr[ni], acc[mi][ni], 0, 0, 0);

        cur ^= 1;
    }

    // epilogue: C/D layout col = lane&15, row = (lane>>4)*4 + reg
    int crow0 = bi * 128 + wr * 64 + (lane >> 4) * 4;
    int ccol0 = bj * 128 + wc * 64 + (lane & 15);
    if (heavy) {
#pragma unroll
        for (int mi = 0; mi < 4; ++mi)
#pragma unroll
            for (int ni = 0; ni < 4; ++ni) {
                float* cp = C + (size_t)(crow0 + mi * 16) * NN + ccol0 + ni * 16;
#pragma unroll
                for (int r2 = 0; r2 < 4; ++r2)
                    atomicAdd(&cp[(size_t)r2 * NN], acc[mi][ni][r2]);
            }
    } else {
#pragma unroll
        for (int mi = 0; mi < 4; ++mi)
#pragma unroll
            for (int ni = 0; ni < 4; ++ni) {
                float* cp = C + (size_t)(crow0 + mi * 16) * NN + ccol0 + ni * 16;
#pragma unroll
                for (int r2 = 0; r2 < 4; ++r2)
                    cp[(size_t)r2 * NN] = acc[mi][ni][r2];
            }
    }
}

extern "C" void kernel_launch(void* const* d_in, const int* in_sizes, int n_in,
                              void* d_out, int out_size, void* d_ws, size_t ws_size,
                              hipStream_t stream) {
    const float* A = (const float*)d_in[0];
    const float* B = (const float*)d_in[1];
    float* C = (float*)d_out;
    unsigned short* Ab = (unsigned short*)d_ws;            // 32 MB bf16 A (lower tiles valid)
    unsigned short* Bt = Ab + (size_t)NN * NN;             // 32 MB bf16 B^T (needed tiles valid)
    prep<<<PGRID, 256, 0, stream>>>(A, B, Ab, Bt, C);
    trimm<<<TGRID, 256, 0, stream>>>(Ab, Bt, C);
}